// Round 1
// baseline (649.197 us; speedup 1.0000x reference)
//
#include <hip/hip_runtime.h>

// Problem: B=4, N=512, RBF=32, F=16
// image   (B,N,N,32) f32   d_in[0]
// vectors (B,N,N,3)  f32   d_in[1]
// feat0   (B,N,16,1) f32   d_in[2]
// feat1   (B,N,16,3) f32   d_in[3]
// W00,b00,W01,b01,W10,b10,W11,b11  d_in[4..11]
// out: out1(B,N,16,1) | out2(B,N,16,3) | out3(B,N,16,3) | out4(B,N,16,1) | out5(B,N,16,3)

#define EPS 1e-7f

__global__ __launch_bounds__(256, 4) void conv_fused_kernel(
    const float* __restrict__ image,
    const float* __restrict__ vectors,
    const float* __restrict__ feat0,
    const float* __restrict__ feat1,
    const float* __restrict__ W00, const float* __restrict__ b00,
    const float* __restrict__ W01, const float* __restrict__ b01,
    const float* __restrict__ W10, const float* __restrict__ b10,
    const float* __restrict__ W11, const float* __restrict__ b11,
    float* __restrict__ out)
{
    __shared__ float w_lds[4][16][36];   // [filter][f][rbf], padded 32->36
    __shared__ float red[16][16][12];    // [bt][f][comp(11, pad 12)]

    const int t  = threadIdx.x;
    const int f  = t & 15;
    const int bt = t >> 4;               // 16 b-threads per f
    const int ma = blockIdx.x;           // m*512 + a
    const int m  = ma >> 9;

    // ---- stage weights to LDS: w_lds[filt][f][rbf] = W[rbf][f] ----
    {
        const float* Wp;
        #define STAGE_W(WPTR, FILT)                                  \
            Wp = (WPTR);                                             \
            _Pragma("unroll")                                        \
            for (int j = 0; j < 2; ++j) {                            \
                int e  = t + j * 256;      /* 0..511 */              \
                int r  = e >> 4;                                     \
                int ff = e & 15;                                     \
                w_lds[FILT][ff][r] = Wp[r * 16 + ff];                \
            }
        STAGE_W(W00, 0)
        STAGE_W(W01, 1)
        STAGE_W(W10, 2)
        STAGE_W(W11, 3)
        #undef STAGE_W
    }
    const float bias0 = b00[f];
    const float bias1 = b01[f];
    const float bias2 = b10[f];
    const float bias3 = b11[f];
    __syncthreads();

    const float* imgbase = image   + (size_t)ma * (512 * 32);
    const float* vecbase = vectors + (size_t)ma * (512 * 3);
    const float* f0base  = feat0   + (size_t)m  * (512 * 16);
    const float* f1base  = feat1   + (size_t)m  * (512 * 16 * 3);

    float acc1 = 0.f, acc4 = 0.f;
    float acc2x = 0.f, acc2y = 0.f, acc2z = 0.f;
    float acc3x = 0.f, acc3y = 0.f, acc3z = 0.f;
    float acc5x = 0.f, acc5y = 0.f, acc5z = 0.f;

    // thread's b-range: [bt*32, bt*32+32), processed in 8 groups of 4
    for (int g = 0; g < 8; ++g) {
        const int b0 = bt * 32 + g * 4;

        float r00[4], r01[4], r10[4], r11[4];
        #pragma unroll
        for (int k = 0; k < 4; ++k) {
            r00[k] = bias0; r01[k] = bias1; r10[k] = bias2; r11[k] = bias3;
        }

        #pragma unroll
        for (int c = 0; c < 8; ++c) {
            const float4 w0 = *(const float4*)&w_lds[0][f][c * 4];
            const float4 w1 = *(const float4*)&w_lds[1][f][c * 4];
            const float4 w2 = *(const float4*)&w_lds[2][f][c * 4];
            const float4 w3 = *(const float4*)&w_lds[3][f][c * 4];
            #pragma unroll
            for (int k = 0; k < 4; ++k) {
                const float4 im = *(const float4*)(imgbase + (size_t)(b0 + k) * 32 + c * 4);
                r00[k] = fmaf(im.x, w0.x, r00[k]);
                r00[k] = fmaf(im.y, w0.y, r00[k]);
                r00[k] = fmaf(im.z, w0.z, r00[k]);
                r00[k] = fmaf(im.w, w0.w, r00[k]);
                r01[k] = fmaf(im.x, w1.x, r01[k]);
                r01[k] = fmaf(im.y, w1.y, r01[k]);
                r01[k] = fmaf(im.z, w1.z, r01[k]);
                r01[k] = fmaf(im.w, w1.w, r01[k]);
                r10[k] = fmaf(im.x, w2.x, r10[k]);
                r10[k] = fmaf(im.y, w2.y, r10[k]);
                r10[k] = fmaf(im.z, w2.z, r10[k]);
                r10[k] = fmaf(im.w, w2.w, r10[k]);
                r11[k] = fmaf(im.x, w3.x, r11[k]);
                r11[k] = fmaf(im.y, w3.y, r11[k]);
                r11[k] = fmaf(im.z, w3.z, r11[k]);
                r11[k] = fmaf(im.w, w3.w, r11[k]);
            }
        }

        #pragma unroll
        for (int k = 0; k < 4; ++k) {
            const int b = b0 + k;
            const float* vp = vecbase + b * 3;
            const float vx = vp[0], vy = vp[1], vz = vp[2];
            const float n2 = vx * vx + vy * vy + vz * vz;
            const bool keep = sqrtf(n2) >= EPS;
            const float q01 = keep ? r01[k] : 0.f;
            const float q11 = keep ? r11[k] : 0.f;

            const float f0v = f0base[b * 16 + f];
            const float* f1p = f1base + (size_t)(b * 16 + f) * 3;
            const float u0 = f1p[0], u1 = f1p[1], u2 = f1p[2];

            // out1 += r00 * f0
            acc1 = fmaf(r00[k], f0v, acc1);
            // out2 += v * (r01 * f0)
            const float t01 = q01 * f0v;
            acc2x = fmaf(t01, vx, acc2x);
            acc2y = fmaf(t01, vy, acc2y);
            acc2z = fmaf(t01, vz, acc2z);
            // out3 += r10 * feat1
            acc3x = fmaf(r10[k], u0, acc3x);
            acc3y = fmaf(r10[k], u1, acc3y);
            acc3z = fmaf(r10[k], u2, acc3z);
            // out4 += r11 * (v . feat1)
            const float d = fmaf(vx, u0, fmaf(vy, u1, vz * u2));
            acc4 = fmaf(q11, d, acc4);
            // out5 += r11 * (v x feat1)
            const float c0 = vy * u2 - vz * u1;
            const float c1 = vz * u0 - vx * u2;
            const float c2 = vx * u1 - vy * u0;
            acc5x = fmaf(q11, c0, acc5x);
            acc5y = fmaf(q11, c1, acc5y);
            acc5z = fmaf(q11, c2, acc5z);
        }
    }

    // ---- reduce across the 16 bt-threads per f ----
    red[bt][f][0]  = acc1;
    red[bt][f][1]  = acc2x;
    red[bt][f][2]  = acc2y;
    red[bt][f][3]  = acc2z;
    red[bt][f][4]  = acc3x;
    red[bt][f][5]  = acc3y;
    red[bt][f][6]  = acc3z;
    red[bt][f][7]  = acc4;
    red[bt][f][8]  = acc5x;
    red[bt][f][9]  = acc5y;
    red[bt][f][10] = acc5z;
    __syncthreads();

    if (t < 176) {
        const int ff = t / 11;
        const int comp = t % 11;
        float s = 0.f;
        #pragma unroll
        for (int i = 0; i < 16; ++i) s += red[i][ff][comp];

        const size_t base16 = (size_t)ma * 16 + ff;
        const size_t base48 = base16 * 3;
        if (comp == 0)      out[base16] = s;
        else if (comp < 4)  out[32768  + base48 + (comp - 1)] = s;
        else if (comp < 7)  out[131072 + base48 + (comp - 4)] = s;
        else if (comp == 7) out[229376 + base16] = s;
        else                out[262144 + base48 + (comp - 8)] = s;
    }
}

extern "C" void kernel_launch(void* const* d_in, const int* in_sizes, int n_in,
                              void* d_out, int out_size, void* d_ws, size_t ws_size,
                              hipStream_t stream) {
    const float* image   = (const float*)d_in[0];
    const float* vectors = (const float*)d_in[1];
    const float* feat0   = (const float*)d_in[2];
    const float* feat1   = (const float*)d_in[3];
    const float* W00 = (const float*)d_in[4];
    const float* b00 = (const float*)d_in[5];
    const float* W01 = (const float*)d_in[6];
    const float* b01 = (const float*)d_in[7];
    const float* W10 = (const float*)d_in[8];
    const float* b10 = (const float*)d_in[9];
    const float* W11 = (const float*)d_in[10];
    const float* b11 = (const float*)d_in[11];
    float* out = (float*)d_out;

    conv_fused_kernel<<<4 * 512, 256, 0, stream>>>(
        image, vectors, feat0, feat1,
        W00, b00, W01, b01, W10, b10, W11, b11, out);
}

// Round 2
// 237.519 us; speedup vs baseline: 2.7332x; 2.7332x over previous
//
#include <hip/hip_runtime.h>

// Problem: B=4, N=512, RBF=32, F=16
// image   (B,N,N,32) f32   d_in[0]
// vectors (B,N,N,3)  f32   d_in[1]
// feat0   (B,N,16,1) f32   d_in[2]
// feat1   (B,N,16,3) f32   d_in[3]
// W00,b00,W01,b01,W10,b10,W11,b11  d_in[4..11]
// out: out1(B,N,16,1) | out2(B,N,16,3) | out3(B,N,16,3) | out4(B,N,16,1) | out5(B,N,16,3)
//
// Radial GEMM via mfma_f32_16x16x32_bf16: A = 16 image rows x 32 rbf,
// B = W (32 x 16). Both packed with the same k-slot convention
// k = (lane>>4)*8 + j, so the contraction is correct independent of the
// hardware's true k mapping (A/B fragments are symmetric). C/D layout is
// the HW-verified col=lane&15, row=(lane>>4)*4+reg.

typedef __attribute__((ext_vector_type(8))) short short8;
typedef __attribute__((ext_vector_type(4))) float f32x4;

#define EPS2 1e-14f

static __device__ __forceinline__ short f2bf(float x) {
    unsigned int u = __float_as_uint(x);
    unsigned int r = (u + 0x7FFFu + ((u >> 16) & 1u)) >> 16;   // RNE
    return (short)r;
}

__global__ __launch_bounds__(256, 4) void conv_mfma_kernel(
    const float* __restrict__ image,
    const float* __restrict__ vectors,
    const float* __restrict__ feat0,
    const float* __restrict__ feat1,
    const float* __restrict__ W00, const float* __restrict__ b00,
    const float* __restrict__ W01, const float* __restrict__ b01,
    const float* __restrict__ W10, const float* __restrict__ b10,
    const float* __restrict__ W11, const float* __restrict__ b11,
    float* __restrict__ out)
{
    __shared__ float red[4][16][12];     // [wave][f][comp(11 pad 12)]

    const int t    = threadIdx.x;
    const int wave = t >> 6;
    const int lane = t & 63;
    const int f    = lane & 15;          // B col / D col
    const int g    = lane >> 4;          // k-group (A/B), row-group (D)
    const int ma   = blockIdx.x;         // m*512 + a
    const int m    = ma >> 9;

    // ---- weight fragments (VGPR-resident, once per block) ----
    short8 wf0, wf1, wf2, wf3;
    float bias0, bias1, bias2, bias3;
    {
        #pragma unroll
        for (int j = 0; j < 8; ++j) {
            const int k = g * 8 + j;
            wf0[j] = f2bf(W00[k * 16 + f]);
            wf1[j] = f2bf(W01[k * 16 + f]);
            wf2[j] = f2bf(W10[k * 16 + f]);
            wf3[j] = f2bf(W11[k * 16 + f]);
        }
        bias0 = b00[f]; bias1 = b01[f]; bias2 = b10[f]; bias3 = b11[f];
    }

    const float* imgbase = image   + (size_t)ma * (512 * 32);
    const float* vecbase = vectors + (size_t)ma * (512 * 3);
    const float* f0base  = feat0   + (size_t)m  * (512 * 16);
    const float* f1base  = feat1   + (size_t)m  * (512 * 16 * 3);

    float acc1 = 0.f, acc4 = 0.f;
    float acc2x = 0.f, acc2y = 0.f, acc2z = 0.f;
    float acc3x = 0.f, acc3y = 0.f, acc3z = 0.f;
    float acc5x = 0.f, acc5y = 0.f, acc5z = 0.f;

    // wave handles b in [wave*128, wave*128+128), 8 tiles of 16
    for (int tt = 0; tt < 8; ++tt) {
        const int b0 = wave * 128 + tt * 16;

        // ---- A fragment: image[b0 + (lane&15)][g*8 .. g*8+8) ----
        const float* arow = imgbase + (size_t)(b0 + f) * 32 + g * 8;
        const float4 a0 = *(const float4*)(arow);
        const float4 a1 = *(const float4*)(arow + 4);
        short8 af;
        af[0] = f2bf(a0.x); af[1] = f2bf(a0.y);
        af[2] = f2bf(a0.z); af[3] = f2bf(a0.w);
        af[4] = f2bf(a1.x); af[5] = f2bf(a1.y);
        af[6] = f2bf(a1.z); af[7] = f2bf(a1.w);

        f32x4 d0 = {0.f, 0.f, 0.f, 0.f};
        f32x4 d1 = {0.f, 0.f, 0.f, 0.f};
        f32x4 d2 = {0.f, 0.f, 0.f, 0.f};
        f32x4 d3 = {0.f, 0.f, 0.f, 0.f};
        d0 = __builtin_amdgcn_mfma_f32_16x16x32_bf16(af, wf0, d0, 0, 0, 0);
        d1 = __builtin_amdgcn_mfma_f32_16x16x32_bf16(af, wf1, d1, 0, 0, 0);
        d2 = __builtin_amdgcn_mfma_f32_16x16x32_bf16(af, wf2, d2, 0, 0, 0);
        d3 = __builtin_amdgcn_mfma_f32_16x16x32_bf16(af, wf3, d3, 0, 0, 0);

        // ---- einsum tail: lane owns b = b0 + 4*g + reg, its f ----
        #pragma unroll
        for (int reg = 0; reg < 4; ++reg) {
            const int b = b0 + 4 * g + reg;

            const float* vp = vecbase + b * 3;
            const float vx = vp[0], vy = vp[1], vz = vp[2];
            const float n2 = vx * vx + vy * vy + vz * vz;
            const bool keep = n2 >= EPS2;

            const float f0v = f0base[b * 16 + f];
            const float* f1p = f1base + (size_t)(b * 16 + f) * 3;
            const float u0 = f1p[0], u1 = f1p[1], u2 = f1p[2];

            const float r00 = d0[reg] + bias0;
            const float r01 = keep ? (d1[reg] + bias1) : 0.f;
            const float r10 = d2[reg] + bias2;
            const float r11 = keep ? (d3[reg] + bias3) : 0.f;

            // out1 += r00 * f0
            acc1 = fmaf(r00, f0v, acc1);
            // out2 += v * (r01 * f0)
            const float t01 = r01 * f0v;
            acc2x = fmaf(t01, vx, acc2x);
            acc2y = fmaf(t01, vy, acc2y);
            acc2z = fmaf(t01, vz, acc2z);
            // out3 += r10 * feat1
            acc3x = fmaf(r10, u0, acc3x);
            acc3y = fmaf(r10, u1, acc3y);
            acc3z = fmaf(r10, u2, acc3z);
            // out4 += r11 * (v . feat1)
            const float d = fmaf(vx, u0, fmaf(vy, u1, vz * u2));
            acc4 = fmaf(r11, d, acc4);
            // out5 += r11 * (v x feat1)
            const float c0 = vy * u2 - vz * u1;
            const float c1 = vz * u0 - vx * u2;
            const float c2 = vx * u1 - vy * u0;
            acc5x = fmaf(r11, c0, acc5x);
            acc5y = fmaf(r11, c1, acc5y);
            acc5z = fmaf(r11, c2, acc5z);
        }
    }

    // ---- in-wave reduce over the 4 lane-groups sharing f ----
    #define WRED(x) x += __shfl_xor(x, 16); x += __shfl_xor(x, 32);
    WRED(acc1)  WRED(acc2x) WRED(acc2y) WRED(acc2z)
    WRED(acc3x) WRED(acc3y) WRED(acc3z) WRED(acc4)
    WRED(acc5x) WRED(acc5y) WRED(acc5z)
    #undef WRED

    if (lane < 16) {
        red[wave][f][0]  = acc1;
        red[wave][f][1]  = acc2x;
        red[wave][f][2]  = acc2y;
        red[wave][f][3]  = acc2z;
        red[wave][f][4]  = acc3x;
        red[wave][f][5]  = acc3y;
        red[wave][f][6]  = acc3z;
        red[wave][f][7]  = acc4;
        red[wave][f][8]  = acc5x;
        red[wave][f][9]  = acc5y;
        red[wave][f][10] = acc5z;
    }
    __syncthreads();

    if (t < 176) {
        const int ff = t / 11;
        const int comp = t % 11;
        float s = red[0][ff][comp] + red[1][ff][comp]
                + red[2][ff][comp] + red[3][ff][comp];

        const size_t base16 = (size_t)ma * 16 + ff;
        const size_t base48 = base16 * 3;
        if (comp == 0)      out[base16] = s;
        else if (comp < 4)  out[32768  + base48 + (comp - 1)] = s;
        else if (comp < 7)  out[131072 + base48 + (comp - 4)] = s;
        else if (comp == 7) out[229376 + base16] = s;
        else                out[262144 + base48 + (comp - 8)] = s;
    }
}

extern "C" void kernel_launch(void* const* d_in, const int* in_sizes, int n_in,
                              void* d_out, int out_size, void* d_ws, size_t ws_size,
                              hipStream_t stream) {
    const float* image   = (const float*)d_in[0];
    const float* vectors = (const float*)d_in[1];
    const float* feat0   = (const float*)d_in[2];
    const float* feat1   = (const float*)d_in[3];
    const float* W00 = (const float*)d_in[4];
    const float* b00 = (const float*)d_in[5];
    const float* W01 = (const float*)d_in[6];
    const float* b01 = (const float*)d_in[7];
    const float* W10 = (const float*)d_in[8];
    const float* b10 = (const float*)d_in[9];
    const float* W11 = (const float*)d_in[10];
    const float* b11 = (const float*)d_in[11];
    float* out = (float*)d_out;

    conv_mfma_kernel<<<4 * 512, 256, 0, stream>>>(
        image, vectors, feat0, feat1,
        W00, b00, W01, b01, W10, b10, W11, b11, out);
}